// Round 1
// baseline (145.860 us; speedup 1.0000x reference)
//
#include <hip/hip_runtime.h>

#define L  512
#define F  64
#define P  32
#define ZO 128
#define ICHUNK 128

constexpr float EPS_LN   = 1e-10f;
constexpr float EPS_NORM = 1e-3f;

// ---------------------------------------------------------------------------
// Kernel 1: LayerNorm over F, then a = (y@Wa^T + ba)*mask, b = (y@Wb^T + bb)*mask
// One wave per row (F == 64 == wave size). 4 rows per block.
// ---------------------------------------------------------------------------
__global__ __launch_bounds__(256) void k_ln_proj(
    const float* __restrict__ M, const float* __restrict__ mask,
    const float* __restrict__ gamma, const float* __restrict__ beta,
    const float* __restrict__ Wa, const float* __restrict__ ba,
    const float* __restrict__ Wb, const float* __restrict__ bb,
    float* __restrict__ a, float* __restrict__ b) {
  __shared__ float y_lds[4][F];
  const int wave = threadIdx.x >> 6;
  const int lane = threadIdx.x & 63;
  const int row  = blockIdx.x * 4 + wave;

  float m = M[row * F + lane];
  // wave-wide sum (64 lanes)
  float s = m;
  #pragma unroll
  for (int o = 32; o >= 1; o >>= 1) s += __shfl_xor(s, o);
  float mean = s * (1.0f / F);
  float d = m - mean;
  float v = d * d;
  #pragma unroll
  for (int o = 32; o >= 1; o >>= 1) v += __shfl_xor(v, o);
  float rstd = rsqrtf(v * (1.0f / F) + EPS_LN);
  float y = d * rstd * gamma[lane] + beta[lane];
  y_lds[wave][lane] = y;
  __syncthreads();

  const float mk = mask[row];
  const float* W    = (lane < P) ? Wa : Wb;
  const float* bias = (lane < P) ? ba : bb;
  const int p = lane & (P - 1);
  float acc = 0.f;
  #pragma unroll 8
  for (int f = 0; f < F; ++f) acc += y_lds[wave][f] * W[p * F + f];
  acc = (acc + bias[p]) * mk;
  float* outp = (lane < P) ? a : b;
  outp[row * P + p] = acc;
}

// ---------------------------------------------------------------------------
// Kernel 2: T[j][z][d] = sum_e b[j][e] * Wz[z*1024 + d*32 + e]
//           (flat: T[j*4096 + seg] with seg = z*32+d, Wz segment = Wz + seg*32)
// Each block handles 8 consecutive j so each Wz segment load is reused 8x.
// ---------------------------------------------------------------------------
__global__ __launch_bounds__(256) void k_T(
    const float* __restrict__ b, const float* __restrict__ Wz,
    float* __restrict__ T) {
  __shared__ float b_lds[8][P];
  const int j0 = blockIdx.x * 8;
  b_lds[threadIdx.x >> 5][threadIdx.x & 31] = b[j0 * P + threadIdx.x];
  __syncthreads();

  for (int seg = threadIdx.x; seg < ZO * P; seg += 256) {
    const float4* wp = (const float4*)(Wz + (size_t)seg * 32);
    float4 w[8];
    #pragma unroll
    for (int q = 0; q < 8; ++q) w[q] = wp[q];
    #pragma unroll
    for (int jj = 0; jj < 8; ++jj) {
      float acc0 = 0.f, acc1 = 0.f, acc2 = 0.f, acc3 = 0.f;
      #pragma unroll
      for (int q = 0; q < 8; ++q) {
        acc0 += w[q].x * b_lds[jj][q * 4 + 0];
        acc1 += w[q].y * b_lds[jj][q * 4 + 1];
        acc2 += w[q].z * b_lds[jj][q * 4 + 2];
        acc3 += w[q].w * b_lds[jj][q * 4 + 3];
      }
      T[(size_t)(j0 + jj) * (ZO * P) + seg] = (acc0 + acc1) + (acc2 + acc3);
    }
  }
}

// ---------------------------------------------------------------------------
// Kernel 3: Z[i,j,z] = (sum_d a[i,d]*T[j,z,d] + bz[z]) / (eps + mask_i*mask_j)
// Thread = (jj in 0..1, z in 0..127); T fragment lives in 8 float4 VGPRs.
// a-chunk staged in LDS, read wave-uniform (broadcast). Stores coalesced
// (lane == consecutive z -> 256 B / wave).
// ---------------------------------------------------------------------------
__global__ __launch_bounds__(256) void k_z(
    const float* __restrict__ a, const float* __restrict__ mask,
    const float* __restrict__ T, const float* __restrict__ bz,
    float* __restrict__ Z) {
  __shared__ float a_lds[ICHUNK * P];   // 16 KB
  __shared__ float inv_lds[2][ICHUNK];  // 1 KB
  const int t  = threadIdx.x;
  const int jj = t >> 7;        // 0..1
  const int z  = t & 127;
  const int j  = blockIdx.x * 2 + jj;
  const int i0 = blockIdx.y * ICHUNK;

  // stage a-chunk (coalesced float loads)
  for (int idx = t; idx < ICHUNK * P; idx += 256)
    a_lds[idx] = a[i0 * P + idx];
  // stage 1/(eps + mask_i*mask_j) for both j of this block
  {
    const int il = t & 127;
    const int jl = t >> 7;
    const float mj = mask[blockIdx.x * 2 + jl];
    inv_lds[jl][il] = 1.0f / (EPS_NORM + mask[i0 + il] * mj);
  }
  __syncthreads();

  // T fragment: 32 contiguous floats for this (j, z)
  float4 tw[8];
  const float4* tp = (const float4*)(T + ((size_t)j * ZO + z) * P);
  #pragma unroll
  for (int q = 0; q < 8; ++q) tw[q] = tp[q];
  const float bzv = bz[z];

  float* outbase = Z + (size_t)i0 * (L * ZO) + (size_t)j * ZO + z;
  for (int i = 0; i < ICHUNK; ++i) {
    const float4* ap = (const float4*)(a_lds + i * P);
    float acc0 = 0.f, acc1 = 0.f, acc2 = 0.f, acc3 = 0.f;
    #pragma unroll
    for (int q = 0; q < 8; ++q) {
      float4 av = ap[q];
      acc0 += av.x * tw[q].x;
      acc1 += av.y * tw[q].y;
      acc2 += av.z * tw[q].z;
      acc3 += av.w * tw[q].w;
    }
    float acc = ((acc0 + acc1) + (acc2 + acc3) + bzv) * inv_lds[jj][i];
    outbase[(size_t)i * (L * ZO)] = acc;
  }
}

// ---------------------------------------------------------------------------
extern "C" void kernel_launch(void* const* d_in, const int* in_sizes, int n_in,
                              void* d_out, int out_size, void* d_ws, size_t ws_size,
                              hipStream_t stream) {
  const float* M     = (const float*)d_in[0];
  const float* mask  = (const float*)d_in[1];
  const float* gamma = (const float*)d_in[2];
  const float* beta  = (const float*)d_in[3];
  const float* Wa    = (const float*)d_in[4];
  const float* ba    = (const float*)d_in[5];
  const float* Wb    = (const float*)d_in[6];
  const float* bb    = (const float*)d_in[7];
  const float* Wz    = (const float*)d_in[8];
  const float* bz    = (const float*)d_in[9];

  float* Z = (float*)d_out;
  float* a = (float*)d_ws;            // 512*32 f32 = 64 KB
  float* b = a + L * P;               // 64 KB
  float* T = b + L * P;               // 512*128*32 f32 = 8 MB

  k_ln_proj<<<L / 4, 256, 0, stream>>>(M, mask, gamma, beta, Wa, ba, Wb, bb, a, b);
  k_T<<<L / 8, 256, 0, stream>>>(b, Wz, T);
  k_z<<<dim3(L / 2, L / ICHUNK), 256, 0, stream>>>(a, mask, T, bz, Z);
}

// Round 2
// 77.621 us; speedup vs baseline: 1.8791x; 1.8791x over previous
//
#include <hip/hip_runtime.h>

#define L  512
#define F  64
#define P  32
#define ZO 128
#define ICHUNK 128

constexpr float EPS_LN   = 1e-10f;
constexpr float EPS_NORM = 1e-3f;

// ---------------------------------------------------------------------------
// Kernel 1: LayerNorm over F, then a = (y@Wa^T + ba)*mask, b = (y@Wb^T + bb)*mask
// One wave per row (F == 64 == wave size). 4 rows per block.
// ---------------------------------------------------------------------------
__global__ __launch_bounds__(256) void k_ln_proj(
    const float* __restrict__ M, const float* __restrict__ mask,
    const float* __restrict__ gamma, const float* __restrict__ beta,
    const float* __restrict__ Wa, const float* __restrict__ ba,
    const float* __restrict__ Wb, const float* __restrict__ bb,
    float* __restrict__ a, float* __restrict__ b) {
  __shared__ float y_lds[4][F];
  const int wave = threadIdx.x >> 6;
  const int lane = threadIdx.x & 63;
  const int row  = blockIdx.x * 4 + wave;

  float m = M[row * F + lane];
  float s = m;
  #pragma unroll
  for (int o = 32; o >= 1; o >>= 1) s += __shfl_xor(s, o);
  float mean = s * (1.0f / F);
  float d = m - mean;
  float v = d * d;
  #pragma unroll
  for (int o = 32; o >= 1; o >>= 1) v += __shfl_xor(v, o);
  float rstd = rsqrtf(v * (1.0f / F) + EPS_LN);
  float y = d * rstd * gamma[lane] + beta[lane];
  y_lds[wave][lane] = y;
  __syncthreads();

  const float mk = mask[row];
  const float* W    = (lane < P) ? Wa : Wb;
  const float* bias = (lane < P) ? ba : bb;
  const int p = lane & (P - 1);
  float acc = 0.f;
  #pragma unroll 8
  for (int f = 0; f < F; ++f) acc += y_lds[wave][f] * W[p * F + f];
  acc = (acc + bias[p]) * mk;
  float* outp = (lane < P) ? a : b;
  outp[row * P + p] = acc;
}

// ---------------------------------------------------------------------------
// Kernel 2: T[j][z][d] = sum_e b[j][e] * Wz[z*1024 + d*32 + e]
//   flat: T[j*4096 + seg], seg = z*32+d, Wz segment = Wz + seg*32.
// Re-grid vs prev round: 256 blocks (one per CU), thread owns one seg
// (lane-consecutive seg -> coalesced 256B stores), 32-j chunk staged in LDS
// (wave-uniform broadcast reads). Wz fits L2 (512 KB) so the per-lane
// strided register load is paid from cache.
// ---------------------------------------------------------------------------
__global__ __launch_bounds__(256) void k_T(
    const float* __restrict__ b, const float* __restrict__ Wz,
    float* __restrict__ T) {
  __shared__ float b_lds[32][P];
  const int seg = blockIdx.x * 256 + threadIdx.x;   // 0..4095
  const int j0  = blockIdx.y * 32;

  for (int idx = threadIdx.x; idx < 32 * P; idx += 256)
    ((float*)b_lds)[idx] = b[j0 * P + idx];
  __syncthreads();

  float4 w[8];
  const float4* wp = (const float4*)(Wz + (size_t)seg * 32);
  #pragma unroll
  for (int q = 0; q < 8; ++q) w[q] = wp[q];

  #pragma unroll 4
  for (int jj = 0; jj < 32; ++jj) {
    float acc0 = 0.f, acc1 = 0.f, acc2 = 0.f, acc3 = 0.f;
    #pragma unroll
    for (int q = 0; q < 8; ++q) {
      acc0 += w[q].x * b_lds[jj][q * 4 + 0];
      acc1 += w[q].y * b_lds[jj][q * 4 + 1];
      acc2 += w[q].z * b_lds[jj][q * 4 + 2];
      acc3 += w[q].w * b_lds[jj][q * 4 + 3];
    }
    T[(size_t)(j0 + jj) * (ZO * P) + seg] = (acc0 + acc1) + (acc2 + acc3);
  }
}

// ---------------------------------------------------------------------------
// Kernel 3: Z[i,j,z] = (sum_d a[i,d]*T[j,z,d] + bz[z]) / (eps + mask_i*mask_j)
// Thread = (jj in 0..1, z in 0..127); T fragment lives in 8 float4 VGPRs.
// a-chunk staged in LDS, read wave-uniform (broadcast). Stores coalesced
// (lane == consecutive z -> 256 B / wave).
// ---------------------------------------------------------------------------
__global__ __launch_bounds__(256) void k_z(
    const float* __restrict__ a, const float* __restrict__ mask,
    const float* __restrict__ T, const float* __restrict__ bz,
    float* __restrict__ Z) {
  __shared__ float a_lds[ICHUNK * P];   // 16 KB
  __shared__ float inv_lds[2][ICHUNK];  // 1 KB
  const int t  = threadIdx.x;
  const int jj = t >> 7;        // 0..1
  const int z  = t & 127;
  const int j  = blockIdx.x * 2 + jj;
  const int i0 = blockIdx.y * ICHUNK;

  for (int idx = t; idx < ICHUNK * P; idx += 256)
    a_lds[idx] = a[i0 * P + idx];
  {
    const int il = t & 127;
    const int jl = t >> 7;
    const float mj = mask[blockIdx.x * 2 + jl];
    inv_lds[jl][il] = 1.0f / (EPS_NORM + mask[i0 + il] * mj);
  }
  __syncthreads();

  float4 tw[8];
  const float4* tp = (const float4*)(T + ((size_t)j * ZO + z) * P);
  #pragma unroll
  for (int q = 0; q < 8; ++q) tw[q] = tp[q];
  const float bzv = bz[z];

  float* outbase = Z + (size_t)i0 * (L * ZO) + (size_t)j * ZO + z;
  for (int i = 0; i < ICHUNK; ++i) {
    const float4* ap = (const float4*)(a_lds + i * P);
    float acc0 = 0.f, acc1 = 0.f, acc2 = 0.f, acc3 = 0.f;
    #pragma unroll
    for (int q = 0; q < 8; ++q) {
      float4 av = ap[q];
      acc0 += av.x * tw[q].x;
      acc1 += av.y * tw[q].y;
      acc2 += av.z * tw[q].z;
      acc3 += av.w * tw[q].w;
    }
    float acc = ((acc0 + acc1) + (acc2 + acc3) + bzv) * inv_lds[jj][i];
    outbase[(size_t)i * (L * ZO)] = acc;
  }
}

// ---------------------------------------------------------------------------
extern "C" void kernel_launch(void* const* d_in, const int* in_sizes, int n_in,
                              void* d_out, int out_size, void* d_ws, size_t ws_size,
                              hipStream_t stream) {
  const float* M     = (const float*)d_in[0];
  const float* mask  = (const float*)d_in[1];
  const float* gamma = (const float*)d_in[2];
  const float* beta  = (const float*)d_in[3];
  const float* Wa    = (const float*)d_in[4];
  const float* ba    = (const float*)d_in[5];
  const float* Wb    = (const float*)d_in[6];
  const float* bb    = (const float*)d_in[7];
  const float* Wz    = (const float*)d_in[8];
  const float* bz    = (const float*)d_in[9];

  float* Z = (float*)d_out;
  float* a = (float*)d_ws;            // 512*32 f32 = 64 KB
  float* b = a + L * P;               // 64 KB
  float* T = b + L * P;               // 8 MB

  k_ln_proj<<<L / 4, 256, 0, stream>>>(M, mask, gamma, beta, Wa, ba, Wb, bb, a, b);
  k_T<<<dim3((ZO * P) / 256, L / 32), 256, 0, stream>>>(b, Wz, T);
  k_z<<<dim3(L / 2, L / ICHUNK), 256, 0, stream>>>(a, mask, T, bz, Z);
}

// Round 3
// 77.147 us; speedup vs baseline: 1.8907x; 1.0061x over previous
//
#include <hip/hip_runtime.h>

#define L  512
#define F  64
#define P  32
#define ZO 128
#define ICHUNK 128
#define JCH 4   // j-chunk for k_T

constexpr float EPS_LN   = 1e-10f;
constexpr float EPS_NORM = 1e-3f;

// ---------------------------------------------------------------------------
// Kernel 1: LayerNorm over F, then a = (y@Wa^T + ba)*mask, b = (y@Wb^T + bb)*mask
// One wave per row (F == 64 == wave size). 4 rows per block.
// ---------------------------------------------------------------------------
__global__ __launch_bounds__(256) void k_ln_proj(
    const float* __restrict__ M, const float* __restrict__ mask,
    const float* __restrict__ gamma, const float* __restrict__ beta,
    const float* __restrict__ Wa, const float* __restrict__ ba,
    const float* __restrict__ Wb, const float* __restrict__ bb,
    float* __restrict__ a, float* __restrict__ b) {
  __shared__ float y_lds[4][F];
  const int wave = threadIdx.x >> 6;
  const int lane = threadIdx.x & 63;
  const int row  = blockIdx.x * 4 + wave;

  float m = M[row * F + lane];
  float s = m;
  #pragma unroll
  for (int o = 32; o >= 1; o >>= 1) s += __shfl_xor(s, o);
  float mean = s * (1.0f / F);
  float d = m - mean;
  float v = d * d;
  #pragma unroll
  for (int o = 32; o >= 1; o >>= 1) v += __shfl_xor(v, o);
  float rstd = rsqrtf(v * (1.0f / F) + EPS_LN);
  float y = d * rstd * gamma[lane] + beta[lane];
  y_lds[wave][lane] = y;
  __syncthreads();

  const float mk = mask[row];
  const float* W    = (lane < P) ? Wa : Wb;
  const float* bias = (lane < P) ? ba : bb;
  const int p = lane & (P - 1);
  float acc = 0.f;
  #pragma unroll 8
  for (int f = 0; f < F; ++f) acc += y_lds[wave][f] * W[p * F + f];
  acc = (acc + bias[p]) * mk;
  float* outp = (lane < P) ? a : b;
  outp[row * P + p] = acc;
}

// ---------------------------------------------------------------------------
// Kernel 2: T[j][z][d] = sum_e b[j][e] * Wz[z*1024 + d*32 + e]
//   flat: T[j*4096 + seg], seg = z*32+d, Wz segment = Wz + seg*32.
// Round-2 lesson: 256 blocks = 1 wave/SIMD = latency-bound (~45us).
// Now: j-chunk=4, grid dim3(16,128)=2048 blocks -> 8 blocks/CU, latency
// hidden by TLP. Each lane's Wz segment is exactly one 128-B cache line
// (L2-resident, reused by 128 blocks); stores 256 B/wave coalesced.
// ---------------------------------------------------------------------------
__global__ __launch_bounds__(256) void k_T(
    const float* __restrict__ b, const float* __restrict__ Wz,
    float* __restrict__ T) {
  __shared__ float b_lds[JCH][P];
  const int seg = blockIdx.x * 256 + threadIdx.x;   // 0..4095
  const int j0  = blockIdx.y * JCH;

  // 8 x float4 of Wz for this seg (one cache line per lane)
  float4 w[8];
  const float4* wp = (const float4*)(Wz + (size_t)seg * 32);
  #pragma unroll
  for (int q = 0; q < 8; ++q) w[q] = wp[q];

  if (threadIdx.x < JCH * P)
    ((float*)b_lds)[threadIdx.x] = b[j0 * P + threadIdx.x];
  __syncthreads();

  #pragma unroll
  for (int jj = 0; jj < JCH; ++jj) {
    float acc0 = 0.f, acc1 = 0.f, acc2 = 0.f, acc3 = 0.f;
    #pragma unroll
    for (int q = 0; q < 8; ++q) {
      acc0 += w[q].x * b_lds[jj][q * 4 + 0];
      acc1 += w[q].y * b_lds[jj][q * 4 + 1];
      acc2 += w[q].z * b_lds[jj][q * 4 + 2];
      acc3 += w[q].w * b_lds[jj][q * 4 + 3];
    }
    T[(size_t)(j0 + jj) * (ZO * P) + seg] = (acc0 + acc1) + (acc2 + acc3);
  }
}

// ---------------------------------------------------------------------------
// Kernel 3: Z[i,j,z] = (sum_d a[i,d]*T[j,z,d] + bz[z]) / (eps + mask_i*mask_j)
// Thread = (jj in 0..1, z in 0..127); T fragment lives in 8 float4 VGPRs.
// a-chunk staged in LDS, read wave-uniform (broadcast). Stores coalesced
// (lane == consecutive z -> 256 B / wave).
// ---------------------------------------------------------------------------
__global__ __launch_bounds__(256) void k_z(
    const float* __restrict__ a, const float* __restrict__ mask,
    const float* __restrict__ T, const float* __restrict__ bz,
    float* __restrict__ Z) {
  __shared__ float a_lds[ICHUNK * P];   // 16 KB
  __shared__ float inv_lds[2][ICHUNK];  // 1 KB
  const int t  = threadIdx.x;
  const int jj = t >> 7;        // 0..1
  const int z  = t & 127;
  const int j  = blockIdx.x * 2 + jj;
  const int i0 = blockIdx.y * ICHUNK;

  for (int idx = t; idx < ICHUNK * P; idx += 256)
    a_lds[idx] = a[i0 * P + idx];
  {
    const int il = t & 127;
    const int jl = t >> 7;
    const float mj = mask[blockIdx.x * 2 + jl];
    inv_lds[jl][il] = 1.0f / (EPS_NORM + mask[i0 + il] * mj);
  }
  __syncthreads();

  float4 tw[8];
  const float4* tp = (const float4*)(T + ((size_t)j * ZO + z) * P);
  #pragma unroll
  for (int q = 0; q < 8; ++q) tw[q] = tp[q];
  const float bzv = bz[z];

  float* outbase = Z + (size_t)i0 * (L * ZO) + (size_t)j * ZO + z;
  for (int i = 0; i < ICHUNK; ++i) {
    const float4* ap = (const float4*)(a_lds + i * P);
    float acc0 = 0.f, acc1 = 0.f, acc2 = 0.f, acc3 = 0.f;
    #pragma unroll
    for (int q = 0; q < 8; ++q) {
      float4 av = ap[q];
      acc0 += av.x * tw[q].x;
      acc1 += av.y * tw[q].y;
      acc2 += av.z * tw[q].z;
      acc3 += av.w * tw[q].w;
    }
    float acc = ((acc0 + acc1) + (acc2 + acc3) + bzv) * inv_lds[jj][i];
    outbase[(size_t)i * (L * ZO)] = acc;
  }
}

// ---------------------------------------------------------------------------
extern "C" void kernel_launch(void* const* d_in, const int* in_sizes, int n_in,
                              void* d_out, int out_size, void* d_ws, size_t ws_size,
                              hipStream_t stream) {
  const float* M     = (const float*)d_in[0];
  const float* mask  = (const float*)d_in[1];
  const float* gamma = (const float*)d_in[2];
  const float* beta  = (const float*)d_in[3];
  const float* Wa    = (const float*)d_in[4];
  const float* ba    = (const float*)d_in[5];
  const float* Wb    = (const float*)d_in[6];
  const float* bb    = (const float*)d_in[7];
  const float* Wz    = (const float*)d_in[8];
  const float* bz    = (const float*)d_in[9];

  float* Z = (float*)d_out;
  float* a = (float*)d_ws;            // 512*32 f32 = 64 KB
  float* b = a + L * P;               // 64 KB
  float* T = b + L * P;               // 8 MB

  k_ln_proj<<<L / 4, 256, 0, stream>>>(M, mask, gamma, beta, Wa, ba, Wb, bb, a, b);
  k_T<<<dim3((ZO * P) / 256, L / JCH), 256, 0, stream>>>(b, Wz, T);
  k_z<<<dim3(L / 2, L / ICHUNK), 256, 0, stream>>>(a, mask, T, bz, Z);
}

// Round 4
// 69.977 us; speedup vs baseline: 2.0844x; 1.1025x over previous
//
#include <hip/hip_runtime.h>

#define L  512
#define F  64
#define P  32
#define ZO 128
#define ICHUNK 128
#define JCH 4   // j-chunk for k_T

constexpr float EPS_LN   = 1e-10f;
constexpr float EPS_NORM = 1e-3f;

// ---------------------------------------------------------------------------
// Kernel 1: LayerNorm over F, then a = (y@Wa^T + ba)*mask, b = (y@Wb^T + bb)*mask
// One wave per row (F == 64 == wave size). 4 rows per block.
// ---------------------------------------------------------------------------
__global__ __launch_bounds__(256) void k_ln_proj(
    const float* __restrict__ M, const float* __restrict__ mask,
    const float* __restrict__ gamma, const float* __restrict__ beta,
    const float* __restrict__ Wa, const float* __restrict__ ba,
    const float* __restrict__ Wb, const float* __restrict__ bb,
    float* __restrict__ a, float* __restrict__ b) {
  __shared__ float y_lds[4][F];
  const int wave = threadIdx.x >> 6;
  const int lane = threadIdx.x & 63;
  const int row  = blockIdx.x * 4 + wave;

  float m = M[row * F + lane];
  float s = m;
  #pragma unroll
  for (int o = 32; o >= 1; o >>= 1) s += __shfl_xor(s, o);
  float mean = s * (1.0f / F);
  float d = m - mean;
  float v = d * d;
  #pragma unroll
  for (int o = 32; o >= 1; o >>= 1) v += __shfl_xor(v, o);
  float rstd = rsqrtf(v * (1.0f / F) + EPS_LN);
  float y = d * rstd * gamma[lane] + beta[lane];
  y_lds[wave][lane] = y;
  __syncthreads();

  const float mk = mask[row];
  const float* W    = (lane < P) ? Wa : Wb;
  const float* bias = (lane < P) ? ba : bb;
  const int p = lane & (P - 1);
  float acc = 0.f;
  #pragma unroll 8
  for (int f = 0; f < F; ++f) acc += y_lds[wave][f] * W[p * F + f];
  acc = (acc + bias[p]) * mk;
  float* outp = (lane < P) ? a : b;
  outp[row * P + p] = acc;
}

// ---------------------------------------------------------------------------
// Kernel 2: T[j][z][d] = sum_e b[j][e] * Wz[z*1024 + d*32 + e]
//   flat: T[j*4096 + seg], seg = z*32+d, Wz segment = Wz + seg*32.
// (Measured ~5-7us; not the bottleneck. Unchanged.)
// ---------------------------------------------------------------------------
__global__ __launch_bounds__(256) void k_T(
    const float* __restrict__ b, const float* __restrict__ Wz,
    float* __restrict__ T) {
  __shared__ float b_lds[JCH][P];
  const int seg = blockIdx.x * 256 + threadIdx.x;   // 0..4095
  const int j0  = blockIdx.y * JCH;

  float4 w[8];
  const float4* wp = (const float4*)(Wz + (size_t)seg * 32);
  #pragma unroll
  for (int q = 0; q < 8; ++q) w[q] = wp[q];

  if (threadIdx.x < JCH * P)
    ((float*)b_lds)[threadIdx.x] = b[j0 * P + threadIdx.x];
  __syncthreads();

  #pragma unroll
  for (int jj = 0; jj < JCH; ++jj) {
    float acc0 = 0.f, acc1 = 0.f, acc2 = 0.f, acc3 = 0.f;
    #pragma unroll
    for (int q = 0; q < 8; ++q) {
      acc0 += w[q].x * b_lds[jj][q * 4 + 0];
      acc1 += w[q].y * b_lds[jj][q * 4 + 1];
      acc2 += w[q].z * b_lds[jj][q * 4 + 2];
      acc3 += w[q].w * b_lds[jj][q * 4 + 3];
    }
    T[(size_t)(j0 + jj) * (ZO * P) + seg] = (acc0 + acc1) + (acc2 + acc3);
  }
}

// ---------------------------------------------------------------------------
// Kernel 3: Z[i,j,z] = (sum_d a[i,d]*T[j,z,d] + bz[z]) / (eps + mask_i*mask_j)
// Round-3 lesson: the old a_lds path issued 8 ds_read_b128 per 32 FMAs ->
// LDS-issue-bound (~68us). a is WAVE-UNIFORM per iter: read it from global
// with uniform addresses so the compiler emits s_load into SGPRs and the
// FMAs take the a operand from an SGPR (v_fmac v, s, v). LDS now only holds
// the 1/(eps+mi*mj) table (one b32 broadcast per iter).
// ---------------------------------------------------------------------------
__global__ __launch_bounds__(256) void k_z(
    const float* __restrict__ a, const float* __restrict__ mask,
    const float* __restrict__ T, const float* __restrict__ bz,
    float* __restrict__ Z) {
  __shared__ float inv_lds[2][ICHUNK];  // 1 KB
  const int t  = threadIdx.x;
  const int jj = t >> 7;        // 0..1
  const int z  = t & 127;
  const int j  = blockIdx.x * 2 + jj;
  const int i0 = blockIdx.y * ICHUNK;

  if (t < 2 * ICHUNK) {
    const int il = t & 127;
    const int jl = t >> 7;
    const float mj = mask[blockIdx.x * 2 + jl];
    inv_lds[jl][il] = 1.0f / (EPS_NORM + mask[i0 + il] * mj);
  }
  __syncthreads();

  // T fragment for this (j,z): 32 contiguous floats in 8 float4 VGPRs
  float4 tw[8];
  const float4* tp = (const float4*)(T + ((size_t)j * ZO + z) * P);
  #pragma unroll
  for (int q = 0; q < 8; ++q) tw[q] = tp[q];
  const float bzv = bz[z];

  const float* __restrict__ abase = a + (size_t)i0 * P;  // uniform base
  float* outbase = Z + (size_t)i0 * (L * ZO) + (size_t)j * ZO + z;
  #pragma unroll 2
  for (int i = 0; i < ICHUNK; ++i) {
    const float* __restrict__ ai = abase + i * P;  // uniform -> s_load
    float acc0 = 0.f, acc1 = 0.f, acc2 = 0.f, acc3 = 0.f;
    #pragma unroll
    for (int q = 0; q < 8; ++q) {
      acc0 += ai[q * 4 + 0] * tw[q].x;
      acc1 += ai[q * 4 + 1] * tw[q].y;
      acc2 += ai[q * 4 + 2] * tw[q].z;
      acc3 += ai[q * 4 + 3] * tw[q].w;
    }
    float acc = ((acc0 + acc1) + (acc2 + acc3) + bzv) * inv_lds[jj][i];
    outbase[(size_t)i * (L * ZO)] = acc;
  }
}

// ---------------------------------------------------------------------------
extern "C" void kernel_launch(void* const* d_in, const int* in_sizes, int n_in,
                              void* d_out, int out_size, void* d_ws, size_t ws_size,
                              hipStream_t stream) {
  const float* M     = (const float*)d_in[0];
  const float* mask  = (const float*)d_in[1];
  const float* gamma = (const float*)d_in[2];
  const float* beta  = (const float*)d_in[3];
  const float* Wa    = (const float*)d_in[4];
  const float* ba    = (const float*)d_in[5];
  const float* Wb    = (const float*)d_in[6];
  const float* bb    = (const float*)d_in[7];
  const float* Wz    = (const float*)d_in[8];
  const float* bz    = (const float*)d_in[9];

  float* Z = (float*)d_out;
  float* a = (float*)d_ws;            // 512*32 f32 = 64 KB
  float* b = a + L * P;               // 64 KB
  float* T = b + L * P;               // 8 MB

  k_ln_proj<<<L / 4, 256, 0, stream>>>(M, mask, gamma, beta, Wa, ba, Wb, bb, a, b);
  k_T<<<dim3((ZO * P) / 256, L / JCH), 256, 0, stream>>>(b, Wz, T);
  k_z<<<dim3(L / 2, L / ICHUNK), 256, 0, stream>>>(a, mask, T, bz, Z);
}

// Round 5
// 67.615 us; speedup vs baseline: 2.1572x; 1.0349x over previous
//
#include <hip/hip_runtime.h>

#define L  512
#define F  64
#define P  32
#define ZO 128
#define ICHUNK 128
#define JCH 16   // j-chunk for k_T

constexpr float EPS_LN   = 1e-10f;
constexpr float EPS_NORM = 1e-3f;

// ---------------------------------------------------------------------------
// Kernel 1: LayerNorm over F, then a = (y@Wa^T + ba)*mask, b = (y@Wb^T + bb)*mask
// One wave per row (F == 64 == wave size). 4 rows per block. (~2us, frozen)
// ---------------------------------------------------------------------------
__global__ __launch_bounds__(256) void k_ln_proj(
    const float* __restrict__ M, const float* __restrict__ mask,
    const float* __restrict__ gamma, const float* __restrict__ beta,
    const float* __restrict__ Wa, const float* __restrict__ ba,
    const float* __restrict__ Wb, const float* __restrict__ bb,
    float* __restrict__ a, float* __restrict__ b) {
  __shared__ float y_lds[4][F];
  const int wave = threadIdx.x >> 6;
  const int lane = threadIdx.x & 63;
  const int row  = blockIdx.x * 4 + wave;

  float m = M[row * F + lane];
  float s = m;
  #pragma unroll
  for (int o = 32; o >= 1; o >>= 1) s += __shfl_xor(s, o);
  float mean = s * (1.0f / F);
  float d = m - mean;
  float v = d * d;
  #pragma unroll
  for (int o = 32; o >= 1; o >>= 1) v += __shfl_xor(v, o);
  float rstd = rsqrtf(v * (1.0f / F) + EPS_LN);
  float y = d * rstd * gamma[lane] + beta[lane];
  y_lds[wave][lane] = y;
  __syncthreads();

  const float mk = mask[row];
  const float* W    = (lane < P) ? Wa : Wb;
  const float* bias = (lane < P) ? ba : bb;
  const int p = lane & (P - 1);
  float acc = 0.f;
  #pragma unroll 8
  for (int f = 0; f < F; ++f) acc += y_lds[wave][f] * W[p * F + f];
  acc = (acc + bias[p]) * mk;
  float* outp = (lane < P) ? a : b;
  outp[row * P + p] = acc;
}

// ---------------------------------------------------------------------------
// Kernel 2: T[j][z][d] = sum_e b[j][e] * Wz[z*1024 + d*32 + e]
//   flat: T[j*4096 + seg], seg = z*32+d, Wz segment = Wz + seg*32.
// Round-4 lesson: the per-lane Wz load is a 64-line scatter per instr; at
// JCH=4 it was re-done by 128 blocks -> ~536 MB through L2. Now JCH=16
// (scatter amortized 16x, ~134 MB total), b read via thread-uniform
// pointers (no LDS, no barrier; compiler can scalarize to s_load ->
// v_fmac v,s,v like k_z), stores stay 256 B/wave coalesced.
// ---------------------------------------------------------------------------
__global__ __launch_bounds__(256) void k_T(
    const float* __restrict__ b, const float* __restrict__ Wz,
    float* __restrict__ T) {
  const int seg = blockIdx.x * 256 + threadIdx.x;   // 0..4095
  const int j0  = blockIdx.y * JCH;

  float4 w[8];
  const float4* wp = (const float4*)(Wz + (size_t)seg * 32);
  #pragma unroll
  for (int q = 0; q < 8; ++q) w[q] = wp[q];

  #pragma unroll 2
  for (int jj = 0; jj < JCH; ++jj) {
    const float* __restrict__ br = b + (size_t)(j0 + jj) * P;  // uniform
    float acc0 = 0.f, acc1 = 0.f, acc2 = 0.f, acc3 = 0.f;
    #pragma unroll
    for (int q = 0; q < 8; ++q) {
      acc0 += w[q].x * br[q * 4 + 0];
      acc1 += w[q].y * br[q * 4 + 1];
      acc2 += w[q].z * br[q * 4 + 2];
      acc3 += w[q].w * br[q * 4 + 3];
    }
    T[(size_t)(j0 + jj) * (ZO * P) + seg] = (acc0 + acc1) + (acc2 + acc3);
  }
}

// ---------------------------------------------------------------------------
// Kernel 3: Z[i,j,z] = (sum_d a[i,d]*T[j,z,d] + bz[z]) / (eps + mask_i*mask_j)
// a read through uniform pointers (SGPR operand FMAs), T fragment in 8
// float4 VGPRs, stores 256 B/wave coalesced. ~23us ~= write floor. Frozen.
// ---------------------------------------------------------------------------
__global__ __launch_bounds__(256) void k_z(
    const float* __restrict__ a, const float* __restrict__ mask,
    const float* __restrict__ T, const float* __restrict__ bz,
    float* __restrict__ Z) {
  __shared__ float inv_lds[2][ICHUNK];  // 1 KB
  const int t  = threadIdx.x;
  const int jj = t >> 7;        // 0..1
  const int z  = t & 127;
  const int j  = blockIdx.x * 2 + jj;
  const int i0 = blockIdx.y * ICHUNK;

  if (t < 2 * ICHUNK) {
    const int il = t & 127;
    const int jl = t >> 7;
    const float mj = mask[blockIdx.x * 2 + jl];
    inv_lds[jl][il] = 1.0f / (EPS_NORM + mask[i0 + il] * mj);
  }
  __syncthreads();

  float4 tw[8];
  const float4* tp = (const float4*)(T + ((size_t)j * ZO + z) * P);
  #pragma unroll
  for (int q = 0; q < 8; ++q) tw[q] = tp[q];
  const float bzv = bz[z];

  const float* __restrict__ abase = a + (size_t)i0 * P;  // uniform base
  float* outbase = Z + (size_t)i0 * (L * ZO) + (size_t)j * ZO + z;
  #pragma unroll 2
  for (int i = 0; i < ICHUNK; ++i) {
    const float* __restrict__ ai = abase + i * P;  // uniform -> s_load
    float acc0 = 0.f, acc1 = 0.f, acc2 = 0.f, acc3 = 0.f;
    #pragma unroll
    for (int q = 0; q < 8; ++q) {
      acc0 += ai[q * 4 + 0] * tw[q].x;
      acc1 += ai[q * 4 + 1] * tw[q].y;
      acc2 += ai[q * 4 + 2] * tw[q].z;
      acc3 += ai[q * 4 + 3] * tw[q].w;
    }
    float acc = ((acc0 + acc1) + (acc2 + acc3) + bzv) * inv_lds[jj][i];
    outbase[(size_t)i * (L * ZO)] = acc;
  }
}

// ---------------------------------------------------------------------------
extern "C" void kernel_launch(void* const* d_in, const int* in_sizes, int n_in,
                              void* d_out, int out_size, void* d_ws, size_t ws_size,
                              hipStream_t stream) {
  const float* M     = (const float*)d_in[0];
  const float* mask  = (const float*)d_in[1];
  const float* gamma = (const float*)d_in[2];
  const float* beta  = (const float*)d_in[3];
  const float* Wa    = (const float*)d_in[4];
  const float* ba    = (const float*)d_in[5];
  const float* Wb    = (const float*)d_in[6];
  const float* bb    = (const float*)d_in[7];
  const float* Wz    = (const float*)d_in[8];
  const float* bz    = (const float*)d_in[9];

  float* Z = (float*)d_out;
  float* a = (float*)d_ws;            // 512*32 f32 = 64 KB
  float* b = a + L * P;               // 64 KB
  float* T = b + L * P;               // 8 MB

  k_ln_proj<<<L / 4, 256, 0, stream>>>(M, mask, gamma, beta, Wa, ba, Wb, bb, a, b);
  k_T<<<dim3((ZO * P) / 256, L / JCH), 256, 0, stream>>>(b, Wz, T);
  k_z<<<dim3(L / 2, L / ICHUNK), 256, 0, stream>>>(a, mask, T, bz, Z);
}

// Round 7
// 65.951 us; speedup vs baseline: 2.2116x; 1.0252x over previous
//
#include <hip/hip_runtime.h>

#define L  512
#define F  64
#define P  32
#define ZO 128
#define ICH 32   // i-chunk for k_z
#define JCH 16   // j-chunk for k_T

constexpr float EPS_LN   = 1e-10f;
constexpr float EPS_NORM = 1e-3f;

typedef float f32x2 __attribute__((ext_vector_type(2)));

// ---------------------------------------------------------------------------
// Kernel 1: LayerNorm over F, then a = (y@Wa^T + ba)*mask, b = (y@Wb^T + bb)*mask
// One wave per row (F == 64 == wave size). 4 rows per block. (~2us, frozen)
// ---------------------------------------------------------------------------
__global__ __launch_bounds__(256) void k_ln_proj(
    const float* __restrict__ M, const float* __restrict__ mask,
    const float* __restrict__ gamma, const float* __restrict__ beta,
    const float* __restrict__ Wa, const float* __restrict__ ba,
    const float* __restrict__ Wb, const float* __restrict__ bb,
    float* __restrict__ a, float* __restrict__ b) {
  __shared__ float y_lds[4][F];
  const int wave = threadIdx.x >> 6;
  const int lane = threadIdx.x & 63;
  const int row  = blockIdx.x * 4 + wave;

  float m = M[row * F + lane];
  float s = m;
  #pragma unroll
  for (int o = 32; o >= 1; o >>= 1) s += __shfl_xor(s, o);
  float mean = s * (1.0f / F);
  float d = m - mean;
  float v = d * d;
  #pragma unroll
  for (int o = 32; o >= 1; o >>= 1) v += __shfl_xor(v, o);
  float rstd = rsqrtf(v * (1.0f / F) + EPS_LN);
  float y = d * rstd * gamma[lane] + beta[lane];
  y_lds[wave][lane] = y;
  __syncthreads();

  const float mk = mask[row];
  const float* W    = (lane < P) ? Wa : Wb;
  const float* bias = (lane < P) ? ba : bb;
  const int p = lane & (P - 1);
  float acc = 0.f;
  #pragma unroll 8
  for (int f = 0; f < F; ++f) acc += y_lds[wave][f] * W[p * F + f];
  acc = (acc + bias[p]) * mk;
  float* outp = (lane < P) ? a : b;
  outp[row * P + p] = acc;
}

// ---------------------------------------------------------------------------
// Kernel 2: T[j][z][d] = sum_e b[j][e] * Wz[z*1024 + d*32 + e]
//   flat: T[j*4096 + seg], seg = z*32+d, Wz segment = Wz + seg*32.
// (R5 form, frozen this round for clean attribution of the k_z change.)
// ---------------------------------------------------------------------------
__global__ __launch_bounds__(256) void k_T(
    const float* __restrict__ b, const float* __restrict__ Wz,
    float* __restrict__ T) {
  const int seg = blockIdx.x * 256 + threadIdx.x;   // 0..4095
  const int j0  = blockIdx.y * JCH;

  float4 w[8];
  const float4* wp = (const float4*)(Wz + (size_t)seg * 32);
  #pragma unroll
  for (int q = 0; q < 8; ++q) w[q] = wp[q];

  #pragma unroll 2
  for (int jj = 0; jj < JCH; ++jj) {
    const float* __restrict__ br = b + (size_t)(j0 + jj) * P;  // uniform
    float acc0 = 0.f, acc1 = 0.f, acc2 = 0.f, acc3 = 0.f;
    #pragma unroll
    for (int q = 0; q < 8; ++q) {
      acc0 += w[q].x * br[q * 4 + 0];
      acc1 += w[q].y * br[q * 4 + 1];
      acc2 += w[q].z * br[q * 4 + 2];
      acc3 += w[q].w * br[q * 4 + 3];
    }
    T[(size_t)(j0 + jj) * (ZO * P) + seg] = (acc0 + acc1) + (acc2 + acc3);
  }
}

// ---------------------------------------------------------------------------
// Kernel 3: Z[i,j,z] = (sum_d a[i,d]*T[j,z,d] + bz[z]) / (eps + mask_i*mask_j)
// One WAVE per j row, lane = z-pair. mask[j] wave-uniform -> no LDS, no
// barrier. T fragment = 64 contiguous floats/lane (16 float4 VGPRs).
// a via uniform pointers (s_load). Stores: f32x2 nontemporal -> one 512-B
// contiguous store per wave per i (4x fewer store instrs than dword path).
// ---------------------------------------------------------------------------
__global__ __launch_bounds__(256) void k_z(
    const float* __restrict__ a, const float* __restrict__ mask,
    const float* __restrict__ T, const float* __restrict__ bz,
    float* __restrict__ Z) {
  const int t  = threadIdx.x;
  const int l  = t & 63;          // lane: z-pair index (z = 2l, 2l+1)
  const int jl = t >> 6;          // wave index -> j offset within block
  const int j  = blockIdx.x * 4 + jl;
  const int i0 = blockIdx.y * ICH;

  // T fragment: rows z=2l and z=2l+1 of T[j] -> 64 consecutive floats
  float4 tw[16];
  const float4* tp = (const float4*)(T + ((size_t)j * ZO + 2 * l) * P);
  #pragma unroll
  for (int q = 0; q < 16; ++q) tw[q] = tp[q];

  const float bzx = bz[2 * l], bzy = bz[2 * l + 1];
  const float mj  = mask[j];      // wave-uniform

  const float* __restrict__ abase = a + (size_t)i0 * P;
  float* outbase = Z + ((size_t)i0 * L + j) * ZO + 2 * l;

  for (int i = 0; i < ICH; ++i) {
    const float* __restrict__ ai = abase + (size_t)i * P;  // uniform -> s_load
    float x0 = 0.f, x1 = 0.f, x2 = 0.f, x3 = 0.f;
    float y0 = 0.f, y1 = 0.f, y2 = 0.f, y3 = 0.f;
    #pragma unroll
    for (int q = 0; q < 8; ++q) {
      float4 av = ((const float4*)ai)[q];
      x0 += av.x * tw[q].x;      x1 += av.y * tw[q].y;
      x2 += av.z * tw[q].z;      x3 += av.w * tw[q].w;
      y0 += av.x * tw[8 + q].x;  y1 += av.y * tw[8 + q].y;
      y2 += av.z * tw[8 + q].z;  y3 += av.w * tw[8 + q].w;
    }
    const float inv = 1.0f / (EPS_NORM + mask[i0 + i] * mj);
    f32x2 o;
    o.x = ((x0 + x1) + (x2 + x3) + bzx) * inv;
    o.y = ((y0 + y1) + (y2 + y3) + bzy) * inv;
    __builtin_nontemporal_store(o, (f32x2*)(outbase + (size_t)i * (L * ZO)));
  }
}

// ---------------------------------------------------------------------------
extern "C" void kernel_launch(void* const* d_in, const int* in_sizes, int n_in,
                              void* d_out, int out_size, void* d_ws, size_t ws_size,
                              hipStream_t stream) {
  const float* M     = (const float*)d_in[0];
  const float* mask  = (const float*)d_in[1];
  const float* gamma = (const float*)d_in[2];
  const float* beta  = (const float*)d_in[3];
  const float* Wa    = (const float*)d_in[4];
  const float* ba    = (const float*)d_in[5];
  const float* Wb    = (const float*)d_in[6];
  const float* bb    = (const float*)d_in[7];
  const float* Wz    = (const float*)d_in[8];
  const float* bz    = (const float*)d_in[9];

  float* Z = (float*)d_out;
  float* a = (float*)d_ws;            // 512*32 f32 = 64 KB
  float* b = a + L * P;               // 64 KB
  float* T = b + L * P;               // 8 MB

  k_ln_proj<<<L / 4, 256, 0, stream>>>(M, mask, gamma, beta, Wa, ba, Wb, bb, a, b);
  k_T<<<dim3((ZO * P) / 256, L / JCH), 256, 0, stream>>>(b, Wz, T);
  k_z<<<dim3(L / 4, L / ICH), 256, 0, stream>>>(a, mask, T, bz, Z);
}

// Round 8
// 58.057 us; speedup vs baseline: 2.5124x; 1.1360x over previous
//
#include <hip/hip_runtime.h>

#define L  512
#define F  64
#define P  32
#define ZO 128
#define ICH 32   // i-chunk for k_z
#define JCH 16   // j-chunk for k_T

constexpr float EPS_LN   = 1e-10f;
constexpr float EPS_NORM = 1e-3f;

typedef float f32x2 __attribute__((ext_vector_type(2)));

// ---------------------------------------------------------------------------
// Kernel 1: LayerNorm over F, then a = (y@Wa^T + ba)*mask, b = (y@Wb^T + bb)*mask
// One wave per row (F == 64 == wave size). 4 rows per block. (~2us, frozen)
// ---------------------------------------------------------------------------
__global__ __launch_bounds__(256) void k_ln_proj(
    const float* __restrict__ M, const float* __restrict__ mask,
    const float* __restrict__ gamma, const float* __restrict__ beta,
    const float* __restrict__ Wa, const float* __restrict__ ba,
    const float* __restrict__ Wb, const float* __restrict__ bb,
    float* __restrict__ a, float* __restrict__ b) {
  __shared__ float y_lds[4][F];
  const int wave = threadIdx.x >> 6;
  const int lane = threadIdx.x & 63;
  const int row  = blockIdx.x * 4 + wave;

  float m = M[row * F + lane];
  float s = m;
  #pragma unroll
  for (int o = 32; o >= 1; o >>= 1) s += __shfl_xor(s, o);
  float mean = s * (1.0f / F);
  float d = m - mean;
  float v = d * d;
  #pragma unroll
  for (int o = 32; o >= 1; o >>= 1) v += __shfl_xor(v, o);
  float rstd = rsqrtf(v * (1.0f / F) + EPS_LN);
  float y = d * rstd * gamma[lane] + beta[lane];
  y_lds[wave][lane] = y;
  __syncthreads();

  const float mk = mask[row];
  const float* W    = (lane < P) ? Wa : Wb;
  const float* bias = (lane < P) ? ba : bb;
  const int p = lane & (P - 1);
  float acc = 0.f;
  #pragma unroll 8
  for (int f = 0; f < F; ++f) acc += y_lds[wave][f] * W[p * F + f];
  acc = (acc + bias[p]) * mk;
  float* outp = (lane < P) ? a : b;
  outp[row * P + p] = acc;
}

// ---------------------------------------------------------------------------
// Kernel 2: T[j][z][d] = sum_e b[j][e] * Wz[z*1024 + d*32 + e]
// (R5 form, ~4-6us, frozen.)
// ---------------------------------------------------------------------------
__global__ __launch_bounds__(256) void k_T(
    const float* __restrict__ b, const float* __restrict__ Wz,
    float* __restrict__ T) {
  const int seg = blockIdx.x * 256 + threadIdx.x;   // 0..4095
  const int j0  = blockIdx.y * JCH;

  float4 w[8];
  const float4* wp = (const float4*)(Wz + (size_t)seg * 32);
  #pragma unroll
  for (int q = 0; q < 8; ++q) w[q] = wp[q];

  #pragma unroll 2
  for (int jj = 0; jj < JCH; ++jj) {
    const float* __restrict__ br = b + (size_t)(j0 + jj) * P;  // uniform
    float acc0 = 0.f, acc1 = 0.f, acc2 = 0.f, acc3 = 0.f;
    #pragma unroll
    for (int q = 0; q < 8; ++q) {
      acc0 += w[q].x * br[q * 4 + 0];
      acc1 += w[q].y * br[q * 4 + 1];
      acc2 += w[q].z * br[q * 4 + 2];
      acc3 += w[q].w * br[q * 4 + 3];
    }
    T[(size_t)(j0 + jj) * (ZO * P) + seg] = (acc0 + acc1) + (acc2 + acc3);
  }
}

// ---------------------------------------------------------------------------
// Kernel 3: Z[i,j,z] = (sum_d a[i,d]*T[j,z,d] + bz[z]) / (eps + mask_i*mask_j)
// One WAVE per j row, lane = z-pair. Round-8 change: SOFTWARE-PIPELINED
// a-row loads (double-buffered prefetch, unroll 2) so the s_waitcnt for
// row i+1 lands after row i's 64 FMAs instead of immediately after issue.
// Attacks the per-iteration load-latency serialization (~200cyc/iter).
// ---------------------------------------------------------------------------
__global__ __launch_bounds__(256) void k_z(
    const float* __restrict__ a, const float* __restrict__ mask,
    const float* __restrict__ T, const float* __restrict__ bz,
    float* __restrict__ Z) {
  const int t  = threadIdx.x;
  const int l  = t & 63;          // lane: z-pair index (z = 2l, 2l+1)
  const int jl = t >> 6;          // wave index -> j offset within block
  const int j  = blockIdx.x * 4 + jl;
  const int i0 = blockIdx.y * ICH;

  // T fragment: rows z=2l and z=2l+1 of T[j] -> 64 consecutive floats
  float4 tw[16];
  const float4* tp = (const float4*)(T + ((size_t)j * ZO + 2 * l) * P);
  #pragma unroll
  for (int q = 0; q < 16; ++q) tw[q] = tp[q];

  const float bzx = bz[2 * l], bzy = bz[2 * l + 1];
  const float mj  = mask[j];      // wave-uniform

  const float* __restrict__ abase = a + (size_t)i0 * P;
  float* outbase = Z + ((size_t)i0 * L + j) * ZO + 2 * l;

  // compute+store one row given its preloaded a-row
  auto body = [&](const float4* areg, int irow) {
    float x0 = 0.f, x1 = 0.f, x2 = 0.f, x3 = 0.f;
    float y0 = 0.f, y1 = 0.f, y2 = 0.f, y3 = 0.f;
    #pragma unroll
    for (int q = 0; q < 8; ++q) {
      float4 av = areg[q];
      x0 += av.x * tw[q].x;      x1 += av.y * tw[q].y;
      x2 += av.z * tw[q].z;      x3 += av.w * tw[q].w;
      y0 += av.x * tw[8 + q].x;  y1 += av.y * tw[8 + q].y;
      y2 += av.z * tw[8 + q].z;  y3 += av.w * tw[8 + q].w;
    }
    const float inv = 1.0f / (EPS_NORM + mask[i0 + irow] * mj);
    f32x2 o;
    o.x = ((x0 + x1) + (x2 + x3) + bzx) * inv;
    o.y = ((y0 + y1) + (y2 + y3) + bzy) * inv;
    __builtin_nontemporal_store(o, (f32x2*)(outbase + (size_t)irow * (L * ZO)));
  };

  float4 a0[8], a1[8];
  #pragma unroll
  for (int q = 0; q < 8; ++q) a0[q] = ((const float4*)abase)[q];

  for (int i = 0; i < ICH; i += 2) {
    // prefetch row i+1 (always valid: ICH even)
    #pragma unroll
    for (int q = 0; q < 8; ++q)
      a1[q] = ((const float4*)(abase + (size_t)(i + 1) * P))[q];
    body(a0, i);
    // prefetch row i+2 (clamped to stay in-bounds on last iter)
    const int inx = (i + 2 < ICH) ? (i + 2) : 0;
    #pragma unroll
    for (int q = 0; q < 8; ++q)
      a0[q] = ((const float4*)(abase + (size_t)inx * P))[q];
    body(a1, i + 1);
  }
}

// ---------------------------------------------------------------------------
extern "C" void kernel_launch(void* const* d_in, const int* in_sizes, int n_in,
                              void* d_out, int out_size, void* d_ws, size_t ws_size,
                              hipStream_t stream) {
  const float* M     = (const float*)d_in[0];
  const float* mask  = (const float*)d_in[1];
  const float* gamma = (const float*)d_in[2];
  const float* beta  = (const float*)d_in[3];
  const float* Wa    = (const float*)d_in[4];
  const float* ba    = (const float*)d_in[5];
  const float* Wb    = (const float*)d_in[6];
  const float* bb    = (const float*)d_in[7];
  const float* Wz    = (const float*)d_in[8];
  const float* bz    = (const float*)d_in[9];

  float* Z = (float*)d_out;
  float* a = (float*)d_ws;            // 512*32 f32 = 64 KB
  float* b = a + L * P;               // 64 KB
  float* T = b + L * P;               // 8 MB

  k_ln_proj<<<L / 4, 256, 0, stream>>>(M, mask, gamma, beta, Wa, ba, Wb, bb, a, b);
  k_T<<<dim3((ZO * P) / 256, L / JCH), 256, 0, stream>>>(b, Wz, T);
  k_z<<<dim3(L / 4, L / ICH), 256, 0, stream>>>(a, mask, T, bz, Z);
}